// Round 1
// baseline (9078.715 us; speedup 1.0000x reference)
//
#include <hip/hip_runtime.h>
#include <hip/hip_bf16.h>

typedef unsigned short u16;

#define NB   4
#define NT   90
#define NIMG 360
#define LL   240
#define DD   64
#define HID  512
#define NJ   2048

#define DEV __device__ __forceinline__

DEV float bf2f(u16 x){ unsigned int u = ((unsigned int)x) << 16; float f; __builtin_memcpy(&f, &u, 4); return f; }
DEV u16 f2bf(float f){ unsigned int u; __builtin_memcpy(&u, &f, 4); unsigned int r = (u + 0x7FFFu + ((u >> 16) & 1u)) >> 16; return (u16)r; }
DEV float sigm(float x){ return 1.f / (1.f + __expf(-x)); }
DEV float tanh_f(float x){ x = fminf(fmaxf(x, -15.f), 15.f); float e = __expf(2.f*x); return (e - 1.f) / (e + 1.f); }

// ---------------- workspace layout (bytes) ----------------
static const size_t G_OFF     = 0;            // u16 [90][240][4][2048]  = 353,894,400 B
static const size_t C1_OFF    = 0;            // fp32 conv1 out (alias over G, dead before G written)
static const size_t C2_OFF    = 132710400;
static const size_t C3_OFF    = 182476800;
static const size_t C4_OFF    = 199065600;
static const size_t C5_OFF    = 221184000;    // ends 243,302,400 < 353,894,400
static const size_t FEATS_OFF = 353894400;    // fp32 [360][240][64]
static const size_t PROJ_OFF  = 376012800;    // fp32 [360][240][64]
static const size_t WWT_OFF   = 398131200;    // fp32 [512][64]   w_w^T
static const size_t WHHP_OFF  = 398262272;    // bf16 [512][2048] whh^T, j-permuted
static const size_t BSUM_OFF  = 400359424;    // fp32 [2048] bih+bhh, j-permuted
static const size_t SW1T_OFF  = 400367616;    // fp32 [512][100]
static const size_t VW1T_OFF  = 400572416;    // fp32 [512][100]
static const size_t HX_OFF    = 400777216;    // fp32 2x[4][512]
static const size_t CX_OFF    = 400793600;    // fp32 2x[4][512]
static const size_t HSEQ_OFF  = 400809984;    // fp32 [90][4][512]
static const size_t WS_NEEDED = 401547264;

// ---------------- direct conv + relu ----------------
template<int K, int S, int P, int OWPT>
__global__ __launch_bounds__(256) void conv_relu(
    const float* __restrict__ in, const float* __restrict__ w, const float* __restrict__ bias,
    float* __restrict__ out, int N, int Cin, int Hin, int Win, int Cout, int Hout, int Wout)
{
    constexpr int L = (OWPT-1)*S + K;
    int OWG = Wout / OWPT;
    int idx = blockIdx.x * 256 + threadIdx.x;
    int total = N * Cout * Hout * OWG;
    if (idx >= total) return;
    int owg = idx % OWG; int tmp = idx / OWG;
    int oh  = tmp % Hout; tmp /= Hout;
    int co  = tmp % Cout; int n = tmp / Cout;
    int ow0 = owg * OWPT;
    float b = bias[co];
    float acc[OWPT];
#pragma unroll
    for (int q = 0; q < OWPT; q++) acc[q] = b;
    const float* wco = w + (size_t)co * Cin * K * K;
    int iw0 = ow0 * S - P;
    for (int ci = 0; ci < Cin; ci++){
        const float* inc = in + ((size_t)(n*Cin + ci)) * Hin * Win;
        const float* wc  = wco + ci * K * K;
#pragma unroll
        for (int kh = 0; kh < K; kh++){
            int ih = oh*S - P + kh;
            if (ih < 0 || ih >= Hin) continue;
            const float* row = inc + (size_t)ih * Win;
            float seg[L];
            if (iw0 >= 0 && iw0 + L <= Win){
#pragma unroll
                for (int i = 0; i < L; i++) seg[i] = row[iw0 + i];
            } else {
#pragma unroll
                for (int i = 0; i < L; i++){ int iw = iw0 + i; seg[i] = (iw >= 0 && iw < Win) ? row[iw] : 0.f; }
            }
#pragma unroll
            for (int kw = 0; kw < K; kw++){
                float wv = wc[kh*K + kw];
#pragma unroll
                for (int q = 0; q < OWPT; q++) acc[q] = fmaf(wv, seg[q*S + kw], acc[q]);
            }
        }
    }
    float* op = out + ((size_t)((n*Cout + co)*Hout + oh)) * Wout + ow0;
    float4 o4;
    o4.x = fmaxf(acc[0], 0.f); o4.y = fmaxf(acc[1], 0.f);
    o4.z = fmaxf(acc[2], 0.f); o4.w = fmaxf(acc[3], 0.f);
    *(float4*)op = o4;
}

// ---------------- feats rearrange:  [n][c][12][20] -> feats[n][l][d] ----------------
__global__ __launch_bounds__(256) void extract_feats(const float* __restrict__ c5, float* __restrict__ feats)
{
    int idx = blockIdx.x * 256 + threadIdx.x;
    if (idx >= NIMG * 64 * 240) return;
    int w = idx % 20; int t1 = idx / 20;
    int h = t1 % 12; t1 /= 12;
    int c = t1 % 64; int n = t1 / 64;
    float v = c5[idx];
    int flat = w*768 + c*12 + h;
    int d = flat / 240, l = flat % 240;
    feats[((size_t)n * LL + l) * DD + d] = v;
}

// ---------------- proj = feats @ proj_w.T + proj_b ----------------
__global__ __launch_bounds__(256) void proj_kernel(
    const float* __restrict__ feats, const float* __restrict__ pw,
    const float* __restrict__ pb, float* __restrict__ proj)
{
    __shared__ float pws[64][65];  // [d][dd]
    __shared__ float fs[4][64];
    int tid = threadIdx.x;
    size_t R0 = (size_t)blockIdx.x * 4;
    for (int i = tid; i < 4096; i += 256){
        int dd = i / 64, d = i % 64;
        pws[d][dd] = pw[dd*64 + d];
    }
    { int r = tid / 64, d = tid % 64; fs[r][d] = feats[(R0 + r)*64 + d]; }
    __syncthreads();
    int r = tid / 64, dd = tid % 64;
    float a = pb[dd];
    for (int d = 0; d < 64; d++) a = fmaf(fs[r][d], pws[d][dd], a);
    proj[(R0 + r)*64 + dd] = a;
}

// ---------------- prep: transposes / permutes / bias combine ----------------
__global__ __launch_bounds__(256) void prep(
    const float* __restrict__ w_w, const float* __restrict__ whh,
    const float* __restrict__ bih, const float* __restrict__ bhh,
    const float* __restrict__ sw1, const float* __restrict__ vw1,
    float* __restrict__ w_wT, u16* __restrict__ whh_p, float* __restrict__ bsum,
    float* __restrict__ sw1T, float* __restrict__ vw1T)
{
    int idx = blockIdx.x * 256 + threadIdx.x;
    int stride = gridDim.x * 256;
    for (int i = idx; i < 512*64; i += stride){
        int k = i / 64, dd = i % 64;
        w_wT[i] = w_w[dd*512 + k];
    }
    for (int i = idx; i < 512*2048; i += stride){
        int k = i / 2048, jj = i % 2048;
        int u = jj >> 2, g = jj & 3, j = g*512 + u;
        whh_p[i] = f2bf(whh[(size_t)j*512 + k]);
    }
    for (int i = idx; i < 2048; i += stride){
        int u = i >> 2, g = i & 3, j = g*512 + u;
        bsum[i] = bih[j] + bhh[j];
    }
    for (int i = idx; i < 512*100; i += stride){
        int k = i / 100, u = i % 100;
        sw1T[i] = sw1[u*512 + k];
        vw1T[i] = vw1[u*512 + k];
    }
}

// ---------------- G[t][l][b][jj] = sum_d feats[m][l][d] * wih[j(jj)][l*64+d] (bf16 out) ----------------
__global__ __launch_bounds__(256, 3) void gcompute(
    const float* __restrict__ feats, const float* __restrict__ wih, u16* __restrict__ G)
{
    __shared__ u16 As[72][66];
    __shared__ u16 Ws[256][66];
    int l  = blockIdx.x;
    int j0 = blockIdx.y * 256;
    int m0 = blockIdx.z * 72;
    int tid = threadIdx.x;

    for (int i = tid; i < 72*64; i += 256){
        int m = i >> 6, d = i & 63;
        As[m][d] = f2bf(feats[((size_t)(m0 + m) * LL + l) * DD + d]);
    }
    for (int i = tid; i < 256*64; i += 256){
        int r = i >> 6, d = i & 63;
        int jj = j0 + r;
        int j  = (jj & 3)*512 + (jj >> 2);
        Ws[r][d] = f2bf(wih[(size_t)j * 15360 + l*64 + d]);
    }
    __syncthreads();

    int tx = tid & 31, ty = tid >> 5;
    float acc[9][8];
#pragma unroll
    for (int i = 0; i < 9; i++)
#pragma unroll
        for (int q = 0; q < 8; q++) acc[i][q] = 0.f;

    for (int k = 0; k < 64; k++){
        float a[9], w[8];
#pragma unroll
        for (int i = 0; i < 9; i++) a[i] = bf2f(As[ty*9 + i][k]);
#pragma unroll
        for (int q = 0; q < 8; q++) w[q] = bf2f(Ws[tx + 32*q][k]);
#pragma unroll
        for (int i = 0; i < 9; i++)
#pragma unroll
            for (int q = 0; q < 8; q++)
                acc[i][q] = fmaf(a[i], w[q], acc[i][q]);
    }

#pragma unroll
    for (int i = 0; i < 9; i++){
        int m = m0 + ty*9 + i;
        int b = m / 90, tt = m % 90;
        size_t base = (((size_t)tt * LL + l) * NB + b) * NJ + j0;
#pragma unroll
        for (int q = 0; q < 8; q++)
            G[base + tx + 32*q] = f2bf(acc[i][q]);
    }
}

// ---------------- one LSTM timestep (32 blocks x 1024 threads) ----------------
__global__ __launch_bounds__(1024) void lstm_step(
    int t,
    const float* __restrict__ proj, const u16* __restrict__ G,
    const float* __restrict__ w_wT, const float* __restrict__ w_b,
    const float* __restrict__ wattn_w, const float* __restrict__ wattn_b,
    const u16* __restrict__ whh_p, const float* __restrict__ bsum,
    const float* __restrict__ hx_in, const float* __restrict__ cx_in,
    float* __restrict__ hx_out, float* __restrict__ cx_out, float* __restrict__ hseq)
{
    __shared__ float hxs[NB][HID];
    __shared__ float apj[NB][DD];
    __shared__ float was[DD];
    __shared__ float es[NB][LL];
    __shared__ float als[NB][LL];
    __shared__ float red[16][NB][64];
    __shared__ float gat[NB][64];

    int tid = threadIdx.x;
    int blk = blockIdx.x;

    for (int i = tid; i < NB*HID; i += 1024) hxs[i >> 9][i & 511] = hx_in[i];
    if (tid < DD) was[tid] = wattn_w[tid];
    __syncthreads();

    // attnproj = hx @ w_w.T + w_b  (k split into 4 quarters)
    {
        int q  = tid >> 8;
        int b  = (tid >> 6) & 3;
        int dd = tid & 63;
        float a = 0.f;
        for (int k = q*128; k < q*128 + 128; k++)
            a = fmaf(hxs[b][k], w_wT[k*64 + dd], a);
        red[q][b][dd] = a;
    }
    __syncthreads();
    if (tid < 256){
        int b = tid >> 6, dd = tid & 63;
        apj[b][dd] = w_b[dd] + red[0][b][dd] + red[1][b][dd] + red[2][b][dd] + red[3][b][dd];
    }
    __syncthreads();

    // e[b][l] = wattn . tanh(proj + apj) + wattn_b
    float wb0 = wattn_b[0];
    for (int it = tid; it < NB*LL; it += 1024){
        int b = it / LL, l = it % LL;
        const float4* pr = (const float4*)(proj + ((size_t)(b*NT + t) * LL + l) * DD);
        float acc = 0.f;
#pragma unroll
        for (int d4 = 0; d4 < 16; d4++){
            float4 v = pr[d4];
            acc = fmaf(tanh_f(v.x + apj[b][d4*4+0]), was[d4*4+0], acc);
            acc = fmaf(tanh_f(v.y + apj[b][d4*4+1]), was[d4*4+1], acc);
            acc = fmaf(tanh_f(v.z + apj[b][d4*4+2]), was[d4*4+2], acc);
            acc = fmaf(tanh_f(v.w + apj[b][d4*4+3]), was[d4*4+3], acc);
        }
        es[b][l] = acc + wb0;
    }
    __syncthreads();

    // softmax over l, one wave per b
    {
        int wv = tid >> 6, ln = tid & 63;
        if (wv < NB){
            float m = -1e30f;
            for (int l = ln; l < LL; l += 64) m = fmaxf(m, es[wv][l]);
#pragma unroll
            for (int off = 32; off; off >>= 1) m = fmaxf(m, __shfl_xor(m, off));
            float s = 0.f;
            for (int l = ln; l < LL; l += 64){ float ex = __expf(es[wv][l] - m); als[wv][l] = ex; s += ex; }
#pragma unroll
            for (int off = 32; off; off >>= 1) s += __shfl_xor(s, off);
            float inv = 1.f / s;
            for (int l = ln; l < LL; l += 64) als[wv][l] *= inv;
        }
    }
    __syncthreads();

    // gates: sum_l alpha*G  +  hx @ whh.T   (l and k split over 16 lq groups)
    int jl = tid & 63, lq = tid >> 6;
    int jj = blk*64 + jl;
    float accb[NB] = {0.f, 0.f, 0.f, 0.f};
    {
        const u16* Gt = G + (size_t)t * LL * NB * NJ;
        for (int l = lq*15; l < lq*15 + 15; l++){
            const u16* gp = Gt + ((size_t)l * NB) * NJ + jj;
#pragma unroll
            for (int b = 0; b < NB; b++)
                accb[b] = fmaf(als[b][l], bf2f(gp[b*NJ]), accb[b]);
        }
        for (int k = lq*32; k < lq*32 + 32; k++){
            float wv2 = bf2f(whh_p[(size_t)k * NJ + jj]);
#pragma unroll
            for (int b = 0; b < NB; b++)
                accb[b] = fmaf(hxs[b][k], wv2, accb[b]);
        }
    }
#pragma unroll
    for (int b = 0; b < NB; b++) red[lq][b][jl] = accb[b];
    __syncthreads();

    if (tid < 256){
        int b = tid >> 6, j2 = tid & 63;
        float s = bsum[blk*64 + j2];
#pragma unroll
        for (int q = 0; q < 16; q++) s += red[q][b][j2];
        gat[b][j2] = s;
    }
    __syncthreads();

    // pointwise LSTM cell: block owns u in [blk*16, blk*16+16)
    if (tid < 64){
        int b = tid >> 4, ul = tid & 15;
        int u = blk*16 + ul;
        float gi = gat[b][ul*4+0];
        float gf = gat[b][ul*4+1];
        float gg = gat[b][ul*4+2];
        float go = gat[b][ul*4+3];
        float c = sigm(gf) * cx_in[b*HID + u] + sigm(gi) * tanhf(gg);
        float h = sigm(go) * tanhf(c);
        cx_out[b*HID + u] = c;
        hx_out[b*HID + u] = h;
        hseq[((size_t)t * NB + b) * HID + u] = h;
    }
}

// ---------------- MLP heads, batched over all (t,b) ----------------
__global__ __launch_bounds__(256) void mlp_kernel(
    const float* __restrict__ hseq,
    const float* __restrict__ sw1T, const float* __restrict__ sb1,
    const float* __restrict__ sw2,  const float* __restrict__ sb2,
    const float* __restrict__ sw3,  const float* __restrict__ sb3,
    const float* __restrict__ sw4,  const float* __restrict__ sb4,
    const float* __restrict__ vw1T, const float* __restrict__ vb1,
    const float* __restrict__ vw2,  const float* __restrict__ vb2,
    const float* __restrict__ vw3,  const float* __restrict__ vb3,
    const float* __restrict__ vw4,  const float* __restrict__ vb4,
    float* __restrict__ out)
{
    __shared__ float h0[HID];
    __shared__ float h1[2][100];
    __shared__ float h2[2][52];
    __shared__ float h3[2][12];
    int tb = blockIdx.x;
    int tid = threadIdx.x;
    for (int i = tid; i < HID; i += 256) h0[i] = hseq[(size_t)tb * HID + i];
    __syncthreads();
    if (tid < 100){
        float a = sb1[tid];
        for (int k = 0; k < HID; k++) a = fmaf(h0[k], sw1T[k*100 + tid], a);
        h1[0][tid] = fmaxf(a, 0.f);
    } else if (tid >= 128 && tid < 228){
        int u = tid - 128;
        float a = vb1[u];
        for (int k = 0; k < HID; k++) a = fmaf(h0[k], vw1T[k*100 + u], a);
        h1[1][u] = fmaxf(a, 0.f);
    }
    __syncthreads();
    if (tid < 50){
        float a = sb2[tid];
        for (int k = 0; k < 100; k++) a = fmaf(h1[0][k], sw2[tid*100 + k], a);
        h2[0][tid] = fmaxf(a, 0.f);
    } else if (tid >= 128 && tid < 178){
        int u = tid - 128;
        float a = vb2[u];
        for (int k = 0; k < 100; k++) a = fmaf(h1[1][k], vw2[u*100 + k], a);
        h2[1][u] = fmaxf(a, 0.f);
    }
    __syncthreads();
    if (tid < 10){
        float a = sb3[tid];
        for (int k = 0; k < 50; k++) a = fmaf(h2[0][k], sw3[tid*50 + k], a);
        h3[0][tid] = fmaxf(a, 0.f);
    } else if (tid >= 128 && tid < 138){
        int u = tid - 128;
        float a = vb3[u];
        for (int k = 0; k < 50; k++) a = fmaf(h2[1][k], vw3[u*50 + k], a);
        h3[1][u] = fmaxf(a, 0.f);
    }
    __syncthreads();
    if (tid == 0){
        float a = sb4[0];
        for (int k = 0; k < 10; k++) a = fmaf(h3[0][k], sw4[k], a);
        out[tb] = a;
    } else if (tid == 128){
        float a = vb4[0];
        for (int k = 0; k < 10; k++) a = fmaf(h3[1][k], vw4[k], a);
        out[360 + tb] = a;
    }
}

extern "C" void kernel_launch(void* const* d_in, const int* in_sizes, int n_in,
                              void* d_out, int out_size, void* d_ws, size_t ws_size,
                              hipStream_t stream)
{
    (void)in_sizes; (void)n_in; (void)out_size;
    if (ws_size < WS_NEEDED) return;  // would show as stub-like failure -> diagnose ws_size next round

    const float* cam   = (const float*)d_in[0];
    const float* cw1   = (const float*)d_in[1];  const float* cb1 = (const float*)d_in[2];
    const float* cw2   = (const float*)d_in[3];  const float* cb2 = (const float*)d_in[4];
    const float* cw3   = (const float*)d_in[5];  const float* cb3 = (const float*)d_in[6];
    const float* cw4   = (const float*)d_in[7];  const float* cb4 = (const float*)d_in[8];
    const float* cw5   = (const float*)d_in[9];  const float* cb5 = (const float*)d_in[10];
    const float* pw    = (const float*)d_in[11]; const float* pb  = (const float*)d_in[12];
    const float* w_w   = (const float*)d_in[13]; const float* w_b = (const float*)d_in[14];
    const float* waw   = (const float*)d_in[15]; const float* wab = (const float*)d_in[16];
    const float* wih   = (const float*)d_in[17]; const float* whh = (const float*)d_in[18];
    const float* bih   = (const float*)d_in[19]; const float* bhh = (const float*)d_in[20];
    const float* sw1   = (const float*)d_in[21]; const float* sb1 = (const float*)d_in[22];
    const float* sw2   = (const float*)d_in[23]; const float* sb2 = (const float*)d_in[24];
    const float* sw3   = (const float*)d_in[25]; const float* sb3 = (const float*)d_in[26];
    const float* sw4   = (const float*)d_in[27]; const float* sb4 = (const float*)d_in[28];
    const float* vw1   = (const float*)d_in[29]; const float* vb1 = (const float*)d_in[30];
    const float* vw2   = (const float*)d_in[31]; const float* vb2 = (const float*)d_in[32];
    const float* vw3   = (const float*)d_in[33]; const float* vb3 = (const float*)d_in[34];
    const float* vw4   = (const float*)d_in[35]; const float* vb4 = (const float*)d_in[36];

    char* ws = (char*)d_ws;
    float* c1    = (float*)(ws + C1_OFF);
    float* c2    = (float*)(ws + C2_OFF);
    float* c3    = (float*)(ws + C3_OFF);
    float* c4    = (float*)(ws + C4_OFF);
    float* c5    = (float*)(ws + C5_OFF);
    float* feats = (float*)(ws + FEATS_OFF);
    float* proj  = (float*)(ws + PROJ_OFF);
    float* w_wT  = (float*)(ws + WWT_OFF);
    u16*   whh_p = (u16*)  (ws + WHHP_OFF);
    float* bsum  = (float*)(ws + BSUM_OFF);
    float* sw1T  = (float*)(ws + SW1T_OFF);
    float* vw1T  = (float*)(ws + VW1T_OFF);
    float* hx    = (float*)(ws + HX_OFF);
    float* cx    = (float*)(ws + CX_OFF);
    float* hseq  = (float*)(ws + HSEQ_OFF);
    u16*   G     = (u16*)  (ws + G_OFF);

    // conv stack (fp32 direct, relu fused)
    {
        int total = NIMG*24*48*(80/4);
        conv_relu<5,2,2,4><<<(total+255)/256, 256, 0, stream>>>(cam, cw1, cb1, c1, NIMG, 3, 96, 160, 24, 48, 80);
    }
    {
        int total = NIMG*36*24*(40/4);
        conv_relu<5,2,2,4><<<(total+255)/256, 256, 0, stream>>>(c1, cw2, cb2, c2, NIMG, 24, 48, 80, 36, 24, 40);
    }
    {
        int total = NIMG*48*12*(20/4);
        conv_relu<5,2,2,4><<<(total+255)/256, 256, 0, stream>>>(c2, cw3, cb3, c3, NIMG, 36, 24, 40, 48, 12, 20);
    }
    {
        int total = NIMG*64*12*(20/4);
        conv_relu<3,1,1,4><<<(total+255)/256, 256, 0, stream>>>(c3, cw4, cb4, c4, NIMG, 48, 12, 20, 64, 12, 20);
    }
    {
        int total = NIMG*64*12*(20/4);
        conv_relu<3,1,1,4><<<(total+255)/256, 256, 0, stream>>>(c4, cw5, cb5, c5, NIMG, 64, 12, 20, 64, 12, 20);
    }

    extract_feats<<<(NIMG*64*240 + 255)/256, 256, 0, stream>>>(c5, feats);
    proj_kernel<<<NIMG*LL/4, 256, 0, stream>>>(feats, pw, pb, proj);
    prep<<<2048, 256, 0, stream>>>(w_w, whh, bih, bhh, sw1, vw1, w_wT, whh_p, bsum, sw1T, vw1T);
    gcompute<<<dim3(240, 8, 5), 256, 0, stream>>>(feats, wih, G);

    hipMemsetAsync(ws + HX_OFF, 0, 32768, stream);  // both hx bufs + both cx bufs

    for (int t = 0; t < NT; t++){
        lstm_step<<<32, 1024, 0, stream>>>(t, proj, G, w_wT, w_b, waw, wab, whh_p, bsum,
            hx + (t & 1) * NB * HID, cx + (t & 1) * NB * HID,
            hx + ((t + 1) & 1) * NB * HID, cx + ((t + 1) & 1) * NB * HID, hseq);
    }

    mlp_kernel<<<360, 256, 0, stream>>>(hseq,
        sw1T, sb1, sw2, sb2, sw3, sb3, sw4, sb4,
        vw1T, vb1, vw2, vb2, vw3, vb3, vw4, vb4, (float*)d_out);
}

// Round 2
// 3033.306 us; speedup vs baseline: 2.9930x; 2.9930x over previous
//
#include <hip/hip_runtime.h>
#include <hip/hip_bf16.h>

typedef unsigned short u16;
using bf16x8 = __attribute__((ext_vector_type(8))) short;
using f32x4  = __attribute__((ext_vector_type(4))) float;

#define NB   4
#define NT   90
#define NIMG 360
#define LL   240
#define DD   64
#define HID  512
#define NJ   2048

#define DEV __device__ __forceinline__

DEV float bf2f(u16 x){ unsigned int u = ((unsigned int)x) << 16; float f; __builtin_memcpy(&f, &u, 4); return f; }
DEV u16 f2bf(float f){ unsigned int u; __builtin_memcpy(&u, &f, 4); unsigned int r = (u + 0x7FFFu + ((u >> 16) & 1u)) >> 16; return (u16)r; }
DEV float sigm(float x){ return 1.f / (1.f + __expf(-x)); }
DEV float tanh_f(float x){ x = fminf(fmaxf(x, -15.f), 15.f); float e = __expf(2.f*x); return (e - 1.f) / (e + 1.f); }

// ---------------- workspace layout (bytes) ----------------
static const size_t G_OFF     = 0;            // u16 [90][240][4][2048]  = 353,894,400 B
// conv temporaries alias over the G region (all dead before gcompute writes G):
static const size_t CAMCL_OFF = 0;            // bf16 [360][96][160][8]   = 88,473,600
static const size_t A1_OFF    = 88473600;     // bf16 [360][48][80][24]   = 66,355,200
static const size_t A2_OFF    = 154828800;    // bf16 [360][24][40][40]   = 27,648,000
static const size_t A3_OFF    = 182476800;    // bf16 [360][12][20][48]   =  8,294,400
static const size_t A4_OFF    = 190771200;    // bf16 [360][12][20][64]   = 11,059,200
static const size_t A5_OFF    = 201830400;    // bf16 [360][12][20][64]   = 11,059,200
static const size_t W1B_OFF   = 212889600;    // bf16 [32][224]
static const size_t W2B_OFF   = 212903936;    // bf16 [48][672]
static const size_t W3B_OFF   = 212968448;    // bf16 [48][1120]
static const size_t W4B_OFF   = 213075968;    // bf16 [64][480]
static const size_t W5B_OFF   = 213137408;    // bf16 [64][576]  (ends 213,211,136 < 353,894,400)
static const size_t FEATS_OFF = 353894400;    // fp32 [360][240][64]
static const size_t PROJ_OFF  = 376012800;    // fp32 [360][240][64]
static const size_t WWT_OFF   = 398131200;    // fp32 [512][64]   w_w^T
static const size_t WHHP_OFF  = 398262272;    // bf16 [512][2048] whh^T, j-permuted
static const size_t BSUM_OFF  = 400359424;    // fp32 [2048] bih+bhh, j-permuted
static const size_t SW1T_OFF  = 400367616;    // fp32 [512][100]
static const size_t VW1T_OFF  = 400572416;    // fp32 [512][100]
static const size_t HX_OFF    = 400777216;    // fp32 2x[4][512]
static const size_t CX_OFF    = 400793600;    // fp32 2x[4][512]
static const size_t HSEQ_OFF  = 400809984;    // fp32 [90][4][512]
static const size_t WS_NEEDED = 401547264;

// ---------------- camera NCHW fp32 -> channels-last bf16 [n][h][w][8] ----------------
__global__ __launch_bounds__(256) void cam_to_cl(const float* __restrict__ cam, u16* __restrict__ out)
{
    int i = blockIdx.x * 256 + threadIdx.x;
    if (i >= NIMG * 96 * 160) return;
    int hw = i % (96 * 160);
    int n  = i / (96 * 160);
    const float* p = cam + (size_t)n * 3 * 96 * 160 + hw;
    bf16x8 v;
    v[0] = (short)f2bf(p[0]);
    v[1] = (short)f2bf(p[15360]);
    v[2] = (short)f2bf(p[30720]);
    v[3] = 0; v[4] = 0; v[5] = 0; v[6] = 0; v[7] = 0;
    *(bf16x8*)&out[(size_t)i * 8] = v;
}

// ---------------- weight prep: w[co][ci][kh][kw] fp32 -> wbf[co][cell*CI_PAD+ci] bf16 ----------------
__global__ __launch_bounds__(256) void prep_wbf(
    const float* __restrict__ w, u16* __restrict__ wbf,
    int COUT, int CIN, int CI_PAD, int KHW, int CELLS_PAD, int M_PAD)
{
    int K_PAD = CELLS_PAD * CI_PAD;
    int total = M_PAD * K_PAD;
    for (int i = blockIdx.x * 256 + threadIdx.x; i < total; i += gridDim.x * 256){
        int co = i / K_PAD, kk = i % K_PAD;
        int cell = kk / CI_PAD, ci = kk % CI_PAD;
        float v = 0.f;
        if (co < COUT && cell < KHW * KHW && ci < CIN){
            int kh = cell / KHW, kw = cell % KHW;
            v = w[((size_t)(co * CIN + ci) * KHW + kh) * KHW + kw];
        }
        wbf[i] = f2bf(v);
    }
}

// ---------------- implicit-GEMM MFMA conv (channels-last bf16 in/out) ----------------
// k-order: cell = kh*KHW+kw (ci fastest). Padded cells (>= KHW*KHW) have zero weights and read cell 0.
template<int CI_PAD, int M_PAD, int COUT, int CO_STORE, int KHW, int CELLS_PAD,
         int S, int P, int HIN, int WIN, int HOUT, int WOUT, int TOH, int TOW>
__global__ __launch_bounds__(256) void conv_mfma(
    const u16* __restrict__ in, const u16* __restrict__ wbf,
    const float* __restrict__ bias, u16* __restrict__ out)
{
    constexpr int K_PAD = CELLS_PAD * CI_PAD;
    constexpr int CP8   = CI_PAD / 8;
    constexpr int TIH   = (TOH - 1) * S + KHW;
    constexpr int TIW   = (TOW - 1) * S + KHW;
    constexpr int TIW_H = (TIW + 1) / 2;
    constexpr int NF    = TOH * TOW / 16;
    constexpr int NK0   = K_PAD / 32;
    constexpr int MF    = M_PAD / 16;
    constexpr int NPW   = (NF + 3) / 4;
    constexpr int LDSE  = (S == 2) ? TIH * CP8 * 2 * TIW_H * 8 : TIH * CP8 * TIW * 8;
    static_assert((TOH * TOW) % 16 == 0, "N tile");
    static_assert(K_PAD % 32 == 0, "K pad");

    __shared__ u16 lds[LDSE];

    int tile = blockIdx.x, n = blockIdx.y;
    constexpr int TW_T = WOUT / TOW;
    int th = tile / TW_T, tw = tile % TW_T;
    int oh0 = th * TOH, ow0 = tw * TOW;
    int ih0 = oh0 * S - P, iw0 = ow0 * S - P;
    int tid = threadIdx.x;

    // ---- stage input tile to LDS ----
    constexpr int CHUNKS = TIH * TIW * CP8;
    for (int i = tid; i < CHUNKS; i += 256){
        int c8 = i % CP8; int r2 = i / CP8;
        int iw = r2 % TIW, ih = r2 / TIW;
        int ihg = ih0 + ih, iwg = iw0 + iw;
        bf16x8 v = {0,0,0,0,0,0,0,0};
        if (ihg >= 0 && ihg < HIN && iwg >= 0 && iwg < WIN)
            v = *(const bf16x8*)&in[(((size_t)n * HIN + ihg) * WIN + iwg) * CI_PAD + c8 * 8];
        int off;
        if (S == 2) off = (((ih * CP8 + c8) * 2 + (iw & 1)) * TIW_H + (iw >> 1)) * 8;
        else        off = ((ih * CP8 + c8) * TIW + iw) * 8;
        *(bf16x8*)&lds[off] = v;
    }
    __syncthreads();

    int lane = tid & 63, wv = tid >> 6;
    int col = lane & 15, grp = lane >> 4;

    int ihb[NPW], iwb[NPW];
    bool act[NPW];
#pragma unroll
    for (int i2 = 0; i2 < NPW; i2++){
        int nf = wv + i2 * 4;
        act[i2] = (nf < NF);
        int nfc = act[i2] ? nf : 0;
        int nsp = nfc * 16 + col;
        ihb[i2] = (nsp / TOW) * S;
        iwb[i2] = (nsp % TOW) * S;
    }

    f32x4 acc[MF][NPW];
#pragma unroll
    for (int mf = 0; mf < MF; mf++)
#pragma unroll
        for (int i2 = 0; i2 < NPW; i2++)
            acc[mf][i2] = (f32x4){0.f, 0.f, 0.f, 0.f};

    for (int k0 = 0; k0 < NK0; k0++){
        bf16x8 a[MF];
#pragma unroll
        for (int mf = 0; mf < MF; mf++)
            a[mf] = *(const bf16x8*)&wbf[(size_t)(mf * 16 + col) * K_PAD + k0 * 32 + grp * 8];
        int k8 = k0 * 32 + grp * 8;
        int cell = k8 / CI_PAD;
        int ci0  = k8 - cell * CI_PAD;
        if (cell >= KHW * KHW) cell = 0;     // padded cell: zero weights, any valid addr
        int kh = cell / KHW, kw = cell - (cell / KHW) * KHW;
        int cb = ci0 >> 3;
#pragma unroll
        for (int i2 = 0; i2 < NPW; i2++){
            if (!act[i2]) continue;
            int ih = ihb[i2] + kh;
            int off;
            if (S == 2) off = (((ih * CP8 + cb) * 2 + (kw & 1)) * TIW_H + (iwb[i2] >> 1) + (kw >> 1)) * 8;
            else        off = ((ih * CP8 + cb) * TIW + iwb[i2] + kw) * 8;
            bf16x8 b = *(const bf16x8*)&lds[off];
#pragma unroll
            for (int mf = 0; mf < MF; mf++)
                acc[mf][i2] = __builtin_amdgcn_mfma_f32_16x16x32_bf16(a[mf], b, acc[mf][i2], 0, 0, 0);
        }
    }

    // ---- epilogue: bias + relu -> channels-last bf16 ----
#pragma unroll
    for (int i2 = 0; i2 < NPW; i2++){
        if (!act[i2]) continue;
        int nf = wv + i2 * 4;
        int nsp = nf * 16 + col;
        int oh = oh0 + nsp / TOW, ow = ow0 + nsp % TOW;
        size_t obase = (((size_t)n * HOUT + oh) * WOUT + ow) * CO_STORE;
#pragma unroll
        for (int mf = 0; mf < MF; mf++){
            int cobase = mf * 16 + grp * 4;
#pragma unroll
            for (int r = 0; r < 4; r++){
                int co = cobase + r;
                if (co < CO_STORE){
                    float x = (co < COUT) ? fmaxf(acc[mf][i2][r] + bias[co], 0.f) : 0.f;
                    out[obase + co] = f2bf(x);
                }
            }
        }
    }
}

// ---------------- feats rearrange:  a5_cl[n][h][w][c] -> feats[n][l][d] fp32 ----------------
__global__ __launch_bounds__(256) void extract_feats(const u16* __restrict__ a5, float* __restrict__ feats)
{
    int idx = blockIdx.x * 256 + threadIdx.x;
    if (idx >= NIMG * 12 * 20 * 64) return;
    int c = idx & 63; int t1 = idx >> 6;
    int w = t1 % 20; t1 /= 20;
    int h = t1 % 12; int n = t1 / 12;
    float v = bf2f(a5[idx]);
    int flat = w * 768 + c * 12 + h;
    int d = flat / 240, l = flat % 240;
    feats[((size_t)n * LL + l) * DD + d] = v;
}

// ---------------- proj = feats @ proj_w.T + proj_b ----------------
__global__ __launch_bounds__(256) void proj_kernel(
    const float* __restrict__ feats, const float* __restrict__ pw,
    const float* __restrict__ pb, float* __restrict__ proj)
{
    __shared__ float pws[64][65];  // [d][dd]
    __shared__ float fs[4][64];
    int tid = threadIdx.x;
    size_t R0 = (size_t)blockIdx.x * 4;
    for (int i = tid; i < 4096; i += 256){
        int dd = i / 64, d = i % 64;
        pws[d][dd] = pw[dd*64 + d];
    }
    { int r = tid / 64, d = tid % 64; fs[r][d] = feats[(R0 + r)*64 + d]; }
    __syncthreads();
    int r = tid / 64, dd = tid % 64;
    float a = pb[dd];
    for (int d = 0; d < 64; d++) a = fmaf(fs[r][d], pws[d][dd], a);
    proj[(R0 + r)*64 + dd] = a;
}

// ---------------- prep: transposes / permutes / bias combine ----------------
__global__ __launch_bounds__(256) void prep(
    const float* __restrict__ w_w, const float* __restrict__ whh,
    const float* __restrict__ bih, const float* __restrict__ bhh,
    const float* __restrict__ sw1, const float* __restrict__ vw1,
    float* __restrict__ w_wT, u16* __restrict__ whh_p, float* __restrict__ bsum,
    float* __restrict__ sw1T, float* __restrict__ vw1T)
{
    int idx = blockIdx.x * 256 + threadIdx.x;
    int stride = gridDim.x * 256;
    for (int i = idx; i < 512*64; i += stride){
        int k = i / 64, dd = i % 64;
        w_wT[i] = w_w[dd*512 + k];
    }
    for (int i = idx; i < 512*2048; i += stride){
        int k = i / 2048, jj = i % 2048;
        int u = jj >> 2, g = jj & 3, j = g*512 + u;
        whh_p[i] = f2bf(whh[(size_t)j*512 + k]);
    }
    for (int i = idx; i < 2048; i += stride){
        int u = i >> 2, g = i & 3, j = g*512 + u;
        bsum[i] = bih[j] + bhh[j];
    }
    for (int i = idx; i < 512*100; i += stride){
        int k = i / 100, u = i % 100;
        sw1T[i] = sw1[u*512 + k];
        vw1T[i] = vw1[u*512 + k];
    }
}

// ---------------- G[t][l][b][jj] = sum_d feats[m][l][d] * wih[j(jj)][l*64+d] (bf16 out) ----------------
__global__ __launch_bounds__(256, 3) void gcompute(
    const float* __restrict__ feats, const float* __restrict__ wih, u16* __restrict__ G)
{
    __shared__ u16 As[72][66];
    __shared__ u16 Ws[256][66];
    int l  = blockIdx.x;
    int j0 = blockIdx.y * 256;
    int m0 = blockIdx.z * 72;
    int tid = threadIdx.x;

    for (int i = tid; i < 72*64; i += 256){
        int m = i >> 6, d = i & 63;
        As[m][d] = f2bf(feats[((size_t)(m0 + m) * LL + l) * DD + d]);
    }
    for (int i = tid; i < 256*64; i += 256){
        int r = i >> 6, d = i & 63;
        int jj = j0 + r;
        int j  = (jj & 3)*512 + (jj >> 2);
        Ws[r][d] = f2bf(wih[(size_t)j * 15360 + l*64 + d]);
    }
    __syncthreads();

    int tx = tid & 31, ty = tid >> 5;
    float acc[9][8];
#pragma unroll
    for (int i = 0; i < 9; i++)
#pragma unroll
        for (int q = 0; q < 8; q++) acc[i][q] = 0.f;

    for (int k = 0; k < 64; k++){
        float a[9], w[8];
#pragma unroll
        for (int i = 0; i < 9; i++) a[i] = bf2f(As[ty*9 + i][k]);
#pragma unroll
        for (int q = 0; q < 8; q++) w[q] = bf2f(Ws[tx + 32*q][k]);
#pragma unroll
        for (int i = 0; i < 9; i++)
#pragma unroll
            for (int q = 0; q < 8; q++)
                acc[i][q] = fmaf(a[i], w[q], acc[i][q]);
    }

#pragma unroll
    for (int i = 0; i < 9; i++){
        int m = m0 + ty*9 + i;
        int b = m / 90, tt = m % 90;
        size_t base = (((size_t)tt * LL + l) * NB + b) * NJ + j0;
#pragma unroll
        for (int q = 0; q < 8; q++)
            G[base + tx + 32*q] = f2bf(acc[i][q]);
    }
}

// ---------------- one LSTM timestep (32 blocks x 1024 threads) ----------------
__global__ __launch_bounds__(1024) void lstm_step(
    int t,
    const float* __restrict__ proj, const u16* __restrict__ G,
    const float* __restrict__ w_wT, const float* __restrict__ w_b,
    const float* __restrict__ wattn_w, const float* __restrict__ wattn_b,
    const u16* __restrict__ whh_p, const float* __restrict__ bsum,
    const float* __restrict__ hx_in, const float* __restrict__ cx_in,
    float* __restrict__ hx_out, float* __restrict__ cx_out, float* __restrict__ hseq)
{
    __shared__ float hxs[NB][HID];
    __shared__ float apj[NB][DD];
    __shared__ float was[DD];
    __shared__ float es[NB][LL];
    __shared__ float als[NB][LL];
    __shared__ float red[16][NB][64];
    __shared__ float gat[NB][64];

    int tid = threadIdx.x;
    int blk = blockIdx.x;

    for (int i = tid; i < NB*HID; i += 1024) hxs[i >> 9][i & 511] = hx_in[i];
    if (tid < DD) was[tid] = wattn_w[tid];
    __syncthreads();

    {
        int q  = tid >> 8;
        int b  = (tid >> 6) & 3;
        int dd = tid & 63;
        float a = 0.f;
        for (int k = q*128; k < q*128 + 128; k++)
            a = fmaf(hxs[b][k], w_wT[k*64 + dd], a);
        red[q][b][dd] = a;
    }
    __syncthreads();
    if (tid < 256){
        int b = tid >> 6, dd = tid & 63;
        apj[b][dd] = w_b[dd] + red[0][b][dd] + red[1][b][dd] + red[2][b][dd] + red[3][b][dd];
    }
    __syncthreads();

    float wb0 = wattn_b[0];
    for (int it = tid; it < NB*LL; it += 1024){
        int b = it / LL, l = it % LL;
        const float4* pr = (const float4*)(proj + ((size_t)(b*NT + t) * LL + l) * DD);
        float acc = 0.f;
#pragma unroll
        for (int d4 = 0; d4 < 16; d4++){
            float4 v = pr[d4];
            acc = fmaf(tanh_f(v.x + apj[b][d4*4+0]), was[d4*4+0], acc);
            acc = fmaf(tanh_f(v.y + apj[b][d4*4+1]), was[d4*4+1], acc);
            acc = fmaf(tanh_f(v.z + apj[b][d4*4+2]), was[d4*4+2], acc);
            acc = fmaf(tanh_f(v.w + apj[b][d4*4+3]), was[d4*4+3], acc);
        }
        es[b][l] = acc + wb0;
    }
    __syncthreads();

    {
        int wv = tid >> 6, ln = tid & 63;
        if (wv < NB){
            float m = -1e30f;
            for (int l = ln; l < LL; l += 64) m = fmaxf(m, es[wv][l]);
#pragma unroll
            for (int off = 32; off; off >>= 1) m = fmaxf(m, __shfl_xor(m, off));
            float s = 0.f;
            for (int l = ln; l < LL; l += 64){ float ex = __expf(es[wv][l] - m); als[wv][l] = ex; s += ex; }
#pragma unroll
            for (int off = 32; off; off >>= 1) s += __shfl_xor(s, off);
            float inv = 1.f / s;
            for (int l = ln; l < LL; l += 64) als[wv][l] *= inv;
        }
    }
    __syncthreads();

    int jl = tid & 63, lq = tid >> 6;
    int jj = blk*64 + jl;
    float accb[NB] = {0.f, 0.f, 0.f, 0.f};
    {
        const u16* Gt = G + (size_t)t * LL * NB * NJ;
        for (int l = lq*15; l < lq*15 + 15; l++){
            const u16* gp = Gt + ((size_t)l * NB) * NJ + jj;
#pragma unroll
            for (int b = 0; b < NB; b++)
                accb[b] = fmaf(als[b][l], bf2f(gp[b*NJ]), accb[b]);
        }
        for (int k = lq*32; k < lq*32 + 32; k++){
            float wv2 = bf2f(whh_p[(size_t)k * NJ + jj]);
#pragma unroll
            for (int b = 0; b < NB; b++)
                accb[b] = fmaf(hxs[b][k], wv2, accb[b]);
        }
    }
#pragma unroll
    for (int b = 0; b < NB; b++) red[lq][b][jl] = accb[b];
    __syncthreads();

    if (tid < 256){
        int b = tid >> 6, j2 = tid & 63;
        float s = bsum[blk*64 + j2];
#pragma unroll
        for (int q = 0; q < 16; q++) s += red[q][b][j2];
        gat[b][j2] = s;
    }
    __syncthreads();

    if (tid < 64){
        int b = tid >> 4, ul = tid & 15;
        int u = blk*16 + ul;
        float gi = gat[b][ul*4+0];
        float gf = gat[b][ul*4+1];
        float gg = gat[b][ul*4+2];
        float go = gat[b][ul*4+3];
        float c = sigm(gf) * cx_in[b*HID + u] + sigm(gi) * tanhf(gg);
        float h = sigm(go) * tanhf(c);
        cx_out[b*HID + u] = c;
        hx_out[b*HID + u] = h;
        hseq[((size_t)t * NB + b) * HID + u] = h;
    }
}

// ---------------- MLP heads, batched over all (t,b) ----------------
__global__ __launch_bounds__(256) void mlp_kernel(
    const float* __restrict__ hseq,
    const float* __restrict__ sw1T, const float* __restrict__ sb1,
    const float* __restrict__ sw2,  const float* __restrict__ sb2,
    const float* __restrict__ sw3,  const float* __restrict__ sb3,
    const float* __restrict__ sw4,  const float* __restrict__ sb4,
    const float* __restrict__ vw1T, const float* __restrict__ vb1,
    const float* __restrict__ vw2,  const float* __restrict__ vb2,
    const float* __restrict__ vw3,  const float* __restrict__ vb3,
    const float* __restrict__ vw4,  const float* __restrict__ vb4,
    float* __restrict__ out)
{
    __shared__ float h0[HID];
    __shared__ float h1[2][100];
    __shared__ float h2[2][52];
    __shared__ float h3[2][12];
    int tb = blockIdx.x;
    int tid = threadIdx.x;
    for (int i = tid; i < HID; i += 256) h0[i] = hseq[(size_t)tb * HID + i];
    __syncthreads();
    if (tid < 100){
        float a = sb1[tid];
        for (int k = 0; k < HID; k++) a = fmaf(h0[k], sw1T[k*100 + tid], a);
        h1[0][tid] = fmaxf(a, 0.f);
    } else if (tid >= 128 && tid < 228){
        int u = tid - 128;
        float a = vb1[u];
        for (int k = 0; k < HID; k++) a = fmaf(h0[k], vw1T[k*100 + u], a);
        h1[1][u] = fmaxf(a, 0.f);
    }
    __syncthreads();
    if (tid < 50){
        float a = sb2[tid];
        for (int k = 0; k < 100; k++) a = fmaf(h1[0][k], sw2[tid*100 + k], a);
        h2[0][tid] = fmaxf(a, 0.f);
    } else if (tid >= 128 && tid < 178){
        int u = tid - 128;
        float a = vb2[u];
        for (int k = 0; k < 100; k++) a = fmaf(h1[1][k], vw2[u*100 + k], a);
        h2[1][u] = fmaxf(a, 0.f);
    }
    __syncthreads();
    if (tid < 10){
        float a = sb3[tid];
        for (int k = 0; k < 50; k++) a = fmaf(h2[0][k], sw3[tid*50 + k], a);
        h3[0][tid] = fmaxf(a, 0.f);
    } else if (tid >= 128 && tid < 138){
        int u = tid - 128;
        float a = vb3[u];
        for (int k = 0; k < 50; k++) a = fmaf(h2[1][k], vw3[u*50 + k], a);
        h3[1][u] = fmaxf(a, 0.f);
    }
    __syncthreads();
    if (tid == 0){
        float a = sb4[0];
        for (int k = 0; k < 10; k++) a = fmaf(h3[0][k], sw4[k], a);
        out[tb] = a;
    } else if (tid == 128){
        float a = vb4[0];
        for (int k = 0; k < 10; k++) a = fmaf(h3[1][k], vw4[k], a);
        out[360 + tb] = a;
    }
}

extern "C" void kernel_launch(void* const* d_in, const int* in_sizes, int n_in,
                              void* d_out, int out_size, void* d_ws, size_t ws_size,
                              hipStream_t stream)
{
    (void)in_sizes; (void)n_in; (void)out_size;
    if (ws_size < WS_NEEDED) return;

    const float* cam   = (const float*)d_in[0];
    const float* cw1   = (const float*)d_in[1];  const float* cb1 = (const float*)d_in[2];
    const float* cw2   = (const float*)d_in[3];  const float* cb2 = (const float*)d_in[4];
    const float* cw3   = (const float*)d_in[5];  const float* cb3 = (const float*)d_in[6];
    const float* cw4   = (const float*)d_in[7];  const float* cb4 = (const float*)d_in[8];
    const float* cw5   = (const float*)d_in[9];  const float* cb5 = (const float*)d_in[10];
    const float* pw    = (const float*)d_in[11]; const float* pb  = (const float*)d_in[12];
    const float* w_w   = (const float*)d_in[13]; const float* w_b = (const float*)d_in[14];
    const float* waw   = (const float*)d_in[15]; const float* wab = (const float*)d_in[16];
    const float* wih   = (const float*)d_in[17]; const float* whh = (const float*)d_in[18];
    const float* bih   = (const float*)d_in[19]; const float* bhh = (const float*)d_in[20];
    const float* sw1   = (const float*)d_in[21]; const float* sb1 = (const float*)d_in[22];
    const float* sw2   = (const float*)d_in[23]; const float* sb2 = (const float*)d_in[24];
    const float* sw3   = (const float*)d_in[25]; const float* sb3 = (const float*)d_in[26];
    const float* sw4   = (const float*)d_in[27]; const float* sb4 = (const float*)d_in[28];
    const float* vw1   = (const float*)d_in[29]; const float* vb1 = (const float*)d_in[30];
    const float* vw2   = (const float*)d_in[31]; const float* vb2 = (const float*)d_in[32];
    const float* vw3   = (const float*)d_in[33]; const float* vb3 = (const float*)d_in[34];
    const float* vw4   = (const float*)d_in[35]; const float* vb4 = (const float*)d_in[36];

    char* ws = (char*)d_ws;
    u16*   camcl = (u16*)(ws + CAMCL_OFF);
    u16*   a1    = (u16*)(ws + A1_OFF);
    u16*   a2    = (u16*)(ws + A2_OFF);
    u16*   a3    = (u16*)(ws + A3_OFF);
    u16*   a4    = (u16*)(ws + A4_OFF);
    u16*   a5    = (u16*)(ws + A5_OFF);
    u16*   w1b   = (u16*)(ws + W1B_OFF);
    u16*   w2b   = (u16*)(ws + W2B_OFF);
    u16*   w3b   = (u16*)(ws + W3B_OFF);
    u16*   w4b   = (u16*)(ws + W4B_OFF);
    u16*   w5b   = (u16*)(ws + W5B_OFF);
    float* feats = (float*)(ws + FEATS_OFF);
    float* proj  = (float*)(ws + PROJ_OFF);
    float* w_wT  = (float*)(ws + WWT_OFF);
    u16*   whh_p = (u16*)  (ws + WHHP_OFF);
    float* bsum  = (float*)(ws + BSUM_OFF);
    float* sw1T  = (float*)(ws + SW1T_OFF);
    float* vw1T  = (float*)(ws + VW1T_OFF);
    float* hx    = (float*)(ws + HX_OFF);
    float* cx    = (float*)(ws + CX_OFF);
    float* hseq  = (float*)(ws + HSEQ_OFF);
    u16*   G     = (u16*)  (ws + G_OFF);

    // prep passes
    cam_to_cl<<<(NIMG*96*160 + 255)/256, 256, 0, stream>>>(cam, camcl);
    prep_wbf<<<64, 256, 0, stream>>>(cw1, w1b, 24,  3,  8, 5, 28, 32);
    prep_wbf<<<64, 256, 0, stream>>>(cw2, w2b, 36, 24, 24, 5, 28, 48);
    prep_wbf<<<64, 256, 0, stream>>>(cw3, w3b, 48, 36, 40, 5, 28, 48);
    prep_wbf<<<64, 256, 0, stream>>>(cw4, w4b, 64, 48, 48, 3, 10, 64);
    prep_wbf<<<64, 256, 0, stream>>>(cw5, w5b, 64, 64, 64, 3,  9, 64);

    // conv stack (implicit-GEMM MFMA bf16, channels-last)
    //          CI_PAD M_PAD COUT CO_ST KHW CELLS S  P  HIN WIN HOUT WOUT TOH TOW
    conv_mfma<   8,    32,   24,  24,   5,  28,   2, 2, 96, 160, 48, 80,  8, 40>
        <<<dim3(12, NIMG), 256, 0, stream>>>(camcl, w1b, cb1, a1);
    conv_mfma<  24,    48,   36,  40,   5,  28,   2, 2, 48,  80, 24, 40,  8, 20>
        <<<dim3(6, NIMG), 256, 0, stream>>>(a1, w2b, cb2, a2);
    conv_mfma<  40,    48,   48,  48,   5,  28,   2, 2, 24,  40, 12, 20, 12, 20>
        <<<dim3(1, NIMG), 256, 0, stream>>>(a2, w3b, cb3, a3);
    conv_mfma<  48,    64,   64,  64,   3,  10,   1, 1, 12,  20, 12, 20, 12, 20>
        <<<dim3(1, NIMG), 256, 0, stream>>>(a3, w4b, cb4, a4);
    conv_mfma<  64,    64,   64,  64,   3,   9,   1, 1, 12,  20, 12, 20, 12, 20>
        <<<dim3(1, NIMG), 256, 0, stream>>>(a4, w5b, cb5, a5);

    extract_feats<<<(NIMG*12*20*64 + 255)/256, 256, 0, stream>>>(a5, feats);
    proj_kernel<<<NIMG*LL/4, 256, 0, stream>>>(feats, pw, pb, proj);
    prep<<<2048, 256, 0, stream>>>(w_w, whh, bih, bhh, sw1, vw1, w_wT, whh_p, bsum, sw1T, vw1T);
    gcompute<<<dim3(240, 8, 5), 256, 0, stream>>>(feats, wih, G);

    hipMemsetAsync(ws + HX_OFF, 0, 32768, stream);

    for (int t = 0; t < NT; t++){
        lstm_step<<<32, 1024, 0, stream>>>(t, proj, G, w_wT, w_b, waw, wab, whh_p, bsum,
            hx + (t & 1) * NB * HID, cx + (t & 1) * NB * HID,
            hx + ((t + 1) & 1) * NB * HID, cx + ((t + 1) & 1) * NB * HID, hseq);
    }

    mlp_kernel<<<360, 256, 0, stream>>>(hseq,
        sw1T, sb1, sw2, sb2, sw3, sb3, sw4, sb4,
        vw1T, vb1, vw2, vb2, vw3, vb3, vw4, vb4, (float*)d_out);
}